// Round 1
// baseline (233.495 us; speedup 1.0000x reference)
//
#include <hip/hip_runtime.h>

#define NTOK 4096
#define CH 64
#define LOG2E 1.4426950408889634f

typedef __bf16 bf8 __attribute__((ext_vector_type(8)));
typedef __bf16 bf4 __attribute__((ext_vector_type(4)));
typedef float f4 __attribute__((ext_vector_type(4)));

__device__ __forceinline__ f4 mfma16(bf8 a, bf8 b, f4 c) {
    return __builtin_amdgcn_mfma_f32_16x16x32_bf16(a, b, c, 0, 0, 0);
}

// ---------------- weight transpose + bf16 convert (grid 4, block 256) ----------------
__global__ void transpose_w(const float* __restrict__ wq, const float* __restrict__ wk,
                            const float* __restrict__ wv, const float* __restrict__ wp,
                            __bf16* __restrict__ wqt, __bf16* __restrict__ wkt,
                            __bf16* __restrict__ wvt, __bf16* __restrict__ wpt) {
    int m = blockIdx.x;
    const float* src = (m == 0) ? wq : (m == 1) ? wk : (m == 2) ? wv : wp;
    __bf16* dst      = (m == 0) ? wqt : (m == 1) ? wkt : (m == 2) ? wvt : wpt;
    __shared__ float s[64][65];
    int t = threadIdx.x;
    for (int i = 0; i < 16; ++i) {
        int e = i * 256 + t;
        s[e >> 6][e & 63] = src[e];   // s[in][out]
    }
    __syncthreads();
    int out = t >> 2, seg = t & 3;
    for (int j = 0; j < 16; ++j) {
        int in = seg * 16 + j;
        dst[out * 64 + in] = (__bf16)s[in][out];   // dst[out][in]
    }
}

// ---------------- GroupNorm stage 1: partial sums (grid 256 = 8b x 32 slabs) ----------------
__global__ __launch_bounds__(256) void gn_partial(const float* __restrict__ x,
                                                  float* __restrict__ gpart) {
    int t = threadIdx.x;
    int b = blockIdx.x >> 5, slab = blockIdx.x & 31;
    const float4* xb = (const float4*)(x + (size_t)(b * NTOK + slab * 128) * CH);
    float s = 0.f, ss = 0.f;
    for (int i = 0; i < 8; ++i) {
        int row = (t >> 4) + i * 16;          // 0..127
        float4 v = xb[row * 16 + (t & 15)];   // 4 channels, within one group
        s  += v.x + v.y + v.z + v.w;
        ss += v.x * v.x + v.y * v.y + v.z * v.z + v.w * v.w;
    }
    __shared__ float ls[256], lss[256];
    ls[t] = s; lss[t] = ss;
    __syncthreads();
    if (t < 8) {   // group t: contributors have (t&15) in {2t, 2t+1}
        float a = 0.f, aa = 0.f;
        for (int p = 0; p < 16; ++p) {
            a  += ls[p * 16 + 2 * t]  + ls[p * 16 + 2 * t + 1];
            aa += lss[p * 16 + 2 * t] + lss[p * 16 + 2 * t + 1];
        }
        gpart[((b * 32 + slab) * 8 + t) * 2 + 0] = a;
        gpart[((b * 32 + slab) * 8 + t) * 2 + 1] = aa;
    }
}

// ---------------- GroupNorm stage 2: finalize stats + normalize ----------------
__global__ __launch_bounds__(256) void gn_norm(const float* __restrict__ x,
                                               const float* __restrict__ gpart,
                                               const float* __restrict__ gamma,
                                               const float* __restrict__ beta,
                                               float* __restrict__ h32,
                                               __bf16* __restrict__ h16) {
    int t = threadIdx.x;
    int b = blockIdx.x >> 5, slab = blockIdx.x & 31;
    __shared__ float smean[8], srstd[8], sg[64], sb[64];
    if (t < 64) { sg[t] = gamma[t]; sb[t] = beta[t]; }
    if (t < 8) {
        float a = 0.f, aa = 0.f;
        for (int p = 0; p < 32; ++p) {
            a  += gpart[((b * 32 + p) * 8 + t) * 2 + 0];
            aa += gpart[((b * 32 + p) * 8 + t) * 2 + 1];
        }
        float mean = a * (1.f / 32768.f);
        float var = aa * (1.f / 32768.f) - mean * mean;
        smean[t] = mean;
        srstd[t] = rsqrtf(var + 1e-3f);
    }
    __syncthreads();
    size_t base = (size_t)(b * NTOK + slab * 128) * CH;
    const float4* xb = (const float4*)(x + base);
    float4* hb = (float4*)(h32 + base);
    __bf16* h16b = h16 + base;
    int c4 = (t & 15) * 4, g = c4 >> 3;
    float mean = smean[g], rstd = srstd[g];
    for (int i = 0; i < 8; ++i) {
        int row = (t >> 4) + i * 16;
        int idx = row * 16 + (t & 15);
        float4 v = xb[idx];
        float4 hv;
        hv.x = (v.x - mean) * rstd * sg[c4 + 0] + sb[c4 + 0];
        hv.y = (v.y - mean) * rstd * sg[c4 + 1] + sb[c4 + 1];
        hv.z = (v.z - mean) * rstd * sg[c4 + 2] + sb[c4 + 2];
        hv.w = (v.w - mean) * rstd * sg[c4 + 3] + sb[c4 + 3];
        hb[idx] = hv;
        bf4 hv16;
        hv16[0] = (__bf16)hv.x; hv16[1] = (__bf16)hv.y;
        hv16[2] = (__bf16)hv.z; hv16[3] = (__bf16)hv.w;
        *(bf4*)(h16b + (size_t)idx * 4) = hv16;
    }
}

// ---------------- fused QKV projection (grid 512, 64 rows/block) ----------------
__global__ __launch_bounds__(256) void qkv_kernel(const __bf16* __restrict__ h16,
                                                  const __bf16* __restrict__ wqt,
                                                  const __bf16* __restrict__ wkt,
                                                  const __bf16* __restrict__ wvt,
                                                  const float* __restrict__ bq,
                                                  const float* __restrict__ bk,
                                                  const float* __restrict__ bv,
                                                  __bf16* __restrict__ q,
                                                  __bf16* __restrict__ k,
                                                  __bf16* __restrict__ v) {
    __shared__ __bf16 W[3][64][72];   // [mat][out][in], +8 pad
    int t = threadIdx.x;
    for (int m = 0; m < 3; ++m) {
        const __bf16* src = (m == 0) ? wqt : (m == 1) ? wkt : wvt;
        for (int i = 0; i < 2; ++i) {
            int idx = i * 256 + t, row = idx >> 3, ch = idx & 7;
            *(bf8*)&W[m][row][ch * 8] = *(const bf8*)(src + row * 64 + ch * 8);
        }
    }
    __syncthreads();
    int lane = t & 63, wave = t >> 6, quad = lane >> 4, l15 = lane & 15;
    size_t rowbase = (size_t)blockIdx.x * 64 + wave * 16;
    const __bf16* hrow = h16 + (rowbase + l15) * 64;
    bf8 a0 = *(const bf8*)(hrow + quad * 8);
    bf8 a1 = *(const bf8*)(hrow + 32 + quad * 8);
    for (int m = 0; m < 3; ++m) {
        const float* bias = (m == 0) ? bq : (m == 1) ? bk : bv;
        __bf16* dst = (m == 0) ? q : (m == 1) ? k : v;
        float sc = (m == 0) ? 0.125f * LOG2E : 1.0f;  // fold C^-0.5 and log2(e) into q
        for (int tt = 0; tt < 4; ++tt) {
            int col = l15 + 16 * tt;
            bf8 b0 = *(const bf8*)&W[m][col][quad * 8];
            bf8 b1 = *(const bf8*)&W[m][col][32 + quad * 8];
            f4 acc = {0.f, 0.f, 0.f, 0.f};
            acc = mfma16(a0, b0, acc);
            acc = mfma16(a1, b1, acc);
            float bb = bias[col];
            for (int r = 0; r < 4; ++r) {
                float val = (acc[r] + bb) * sc;
                dst[(rowbase + quad * 4 + r) * 64 + col] = (__bf16)val;
            }
        }
    }
}

// ---------------- V -> V^T per batch (grid 512 = 8b x 64 tiles) ----------------
__global__ __launch_bounds__(256) void vt_kernel(const __bf16* __restrict__ v,
                                                 __bf16* __restrict__ vT) {
    __shared__ __bf16 s[64][72];
    int t = threadIdx.x;
    int b = blockIdx.x >> 6, kt = blockIdx.x & 63;
    const __bf16* src = v + ((size_t)b * NTOK + kt * 64) * 64;
    for (int i = 0; i < 2; ++i) {
        int idx = i * 256 + t, row = idx >> 3, ch = idx & 7;
        *(bf8*)&s[row][ch * 8] = *(const bf8*)(src + row * 64 + ch * 8);
    }
    __syncthreads();
    int d = t >> 2, seg = t & 3;
    bf8 t0, t1;
    for (int j = 0; j < 8; ++j) t0[j] = s[seg * 16 + j][d];
    for (int j = 0; j < 8; ++j) t1[j] = s[seg * 16 + 8 + j][d];
    __bf16* dst = vT + ((size_t)b * 64 + d) * NTOK + kt * 64 + seg * 16;
    *(bf8*)dst = t0;
    *(bf8*)(dst + 8) = t1;
}

// ---------------- flash attention (grid 512 = 8b x 64 q-tiles of 64 rows) ----------------
__global__ __launch_bounds__(256) void attn_kernel(const __bf16* __restrict__ q,
                                                   const __bf16* __restrict__ k,
                                                   const __bf16* __restrict__ vT,
                                                   __bf16* __restrict__ o) {
    __shared__ __bf16 Kl[64][72];       // [key][d]
    __shared__ __bf16 Vl[64][72];       // [d][key]
    __shared__ __bf16 Pl[4][16][72];    // per-wave [qrow][key]
    int t = threadIdx.x;
    int b = blockIdx.x >> 6, qt = blockIdx.x & 63;
    int lane = t & 63, wave = t >> 6, quad = lane >> 4, l15 = lane & 15;

    const __bf16* qrow = q + ((size_t)b * NTOK + qt * 64 + wave * 16 + l15) * 64;
    bf8 aq0 = *(const bf8*)(qrow + quad * 8);
    bf8 aq1 = *(const bf8*)(qrow + 32 + quad * 8);

    f4 O0 = {0.f,0.f,0.f,0.f}, O1 = O0, O2 = O0, O3 = O0;
    float mi[4], li[4];
    for (int r = 0; r < 4; ++r) { mi[r] = -1e30f; li[r] = 0.f; }

    const __bf16* kb = k + (size_t)b * NTOK * 64;
    const __bf16* vb = vT + (size_t)b * 64 * NTOK;

    for (int kt2 = 0; kt2 < 64; ++kt2) {
        __syncthreads();   // previous iter's K/V readers done
        for (int i = 0; i < 2; ++i) {
            int idx = i * 256 + t, row = idx >> 3, ch = idx & 7;
            *(bf8*)&Kl[row][ch * 8] = *(const bf8*)(kb + (size_t)(kt2 * 64 + row) * 64 + ch * 8);
            *(bf8*)&Vl[row][ch * 8] = *(const bf8*)(vb + (size_t)row * NTOK + kt2 * 64 + ch * 8);
        }
        __syncthreads();

        f4 S[4];
        for (int tt = 0; tt < 4; ++tt) {
            bf8 b0 = *(const bf8*)&Kl[l15 + 16 * tt][quad * 8];
            bf8 b1 = *(const bf8*)&Kl[l15 + 16 * tt][32 + quad * 8];
            f4 acc = {0.f,0.f,0.f,0.f};
            acc = mfma16(aq0, b0, acc);
            acc = mfma16(aq1, b1, acc);
            S[tt] = acc;
        }
        float al[4], rs[4];
        for (int r = 0; r < 4; ++r) {
            float mc = fmaxf(fmaxf(S[0][r], S[1][r]), fmaxf(S[2][r], S[3][r]));
            mc = fmaxf(mc, __shfl_xor(mc, 1));
            mc = fmaxf(mc, __shfl_xor(mc, 2));
            mc = fmaxf(mc, __shfl_xor(mc, 4));
            mc = fmaxf(mc, __shfl_xor(mc, 8));
            float mn = fmaxf(mi[r], mc);
            al[r] = __builtin_amdgcn_exp2f(mi[r] - mn);
            mi[r] = mn;
            rs[r] = 0.f;
        }
        for (int tt = 0; tt < 4; ++tt) {
            for (int r = 0; r < 4; ++r) {
                float p = __builtin_amdgcn_exp2f(S[tt][r] - mi[r]);
                rs[r] += p;
                Pl[wave][quad * 4 + r][l15 + 16 * tt] = (__bf16)p;
            }
        }
        for (int r = 0; r < 4; ++r) {
            float s = rs[r];
            s += __shfl_xor(s, 1);
            s += __shfl_xor(s, 2);
            s += __shfl_xor(s, 4);
            s += __shfl_xor(s, 8);
            li[r] = li[r] * al[r] + s;
            O0[r] *= al[r]; O1[r] *= al[r]; O2[r] *= al[r]; O3[r] *= al[r];
        }
        for (int s = 0; s < 2; ++s) {
            bf8 ap = *(const bf8*)&Pl[wave][l15][s * 32 + quad * 8];
            bf8 bv0 = *(const bf8*)&Vl[l15 +  0][s * 32 + quad * 8];
            bf8 bv1 = *(const bf8*)&Vl[l15 + 16][s * 32 + quad * 8];
            bf8 bv2 = *(const bf8*)&Vl[l15 + 32][s * 32 + quad * 8];
            bf8 bv3 = *(const bf8*)&Vl[l15 + 48][s * 32 + quad * 8];
            O0 = mfma16(ap, bv0, O0);
            O1 = mfma16(ap, bv1, O1);
            O2 = mfma16(ap, bv2, O2);
            O3 = mfma16(ap, bv3, O3);
        }
    }
    __bf16* ob = o + ((size_t)b * NTOK + qt * 64 + wave * 16) * 64;
    for (int r = 0; r < 4; ++r) {
        float inv = 1.f / li[r];
        int row = quad * 4 + r;
        ob[row * 64 + l15 +  0] = (__bf16)(O0[r] * inv);
        ob[row * 64 + l15 + 16] = (__bf16)(O1[r] * inv);
        ob[row * 64 + l15 + 32] = (__bf16)(O2[r] * inv);
        ob[row * 64 + l15 + 48] = (__bf16)(O3[r] * inv);
    }
}

// ---------------- final projection + bias + residual (grid 512) ----------------
__global__ __launch_bounds__(256) void final_kernel(const __bf16* __restrict__ o,
                                                    const __bf16* __restrict__ wpt,
                                                    const float* __restrict__ bp,
                                                    const float* __restrict__ h32,
                                                    float* __restrict__ out) {
    __shared__ __bf16 W[64][72];
    int t = threadIdx.x;
    for (int i = 0; i < 2; ++i) {
        int idx = i * 256 + t, row = idx >> 3, ch = idx & 7;
        *(bf8*)&W[row][ch * 8] = *(const bf8*)(wpt + row * 64 + ch * 8);
    }
    __syncthreads();
    int lane = t & 63, wave = t >> 6, quad = lane >> 4, l15 = lane & 15;
    size_t rowbase = (size_t)blockIdx.x * 64 + wave * 16;
    const __bf16* orow = o + (rowbase + l15) * 64;
    bf8 a0 = *(const bf8*)(orow + quad * 8);
    bf8 a1 = *(const bf8*)(orow + 32 + quad * 8);
    for (int tt = 0; tt < 4; ++tt) {
        int col = l15 + 16 * tt;
        bf8 b0 = *(const bf8*)&W[col][quad * 8];
        bf8 b1 = *(const bf8*)&W[col][32 + quad * 8];
        f4 acc = {0.f,0.f,0.f,0.f};
        acc = mfma16(a0, b0, acc);
        acc = mfma16(a1, b1, acc);
        float bias = bp[col];
        for (int r = 0; r < 4; ++r) {
            size_t gi = (rowbase + quad * 4 + r) * 64 + col;
            out[gi] = acc[r] + bias + h32[gi];
        }
    }
}

extern "C" void kernel_launch(void* const* d_in, const int* in_sizes, int n_in,
                              void* d_out, int out_size, void* d_ws, size_t ws_size,
                              hipStream_t stream) {
    const float* x     = (const float*)d_in[0];
    const float* gamma = (const float*)d_in[1];
    const float* beta  = (const float*)d_in[2];
    const float* wq    = (const float*)d_in[3];
    const float* bq    = (const float*)d_in[4];
    const float* wk    = (const float*)d_in[5];
    const float* bk    = (const float*)d_in[6];
    const float* wv    = (const float*)d_in[7];
    const float* bv    = (const float*)d_in[8];
    const float* wp    = (const float*)d_in[9];
    const float* bp    = (const float*)d_in[10];
    float* out = (float*)d_out;

    char* ws = (char*)d_ws;
    const size_t MB = 1024 * 1024;
    float*  h32  = (float*)(ws);                    // 8 MB
    __bf16* h16  = (__bf16*)(ws + 8 * MB);          // 4 MB
    __bf16* qb   = (__bf16*)(ws + 12 * MB);         // 4 MB
    __bf16* kb   = (__bf16*)(ws + 16 * MB);         // 4 MB
    __bf16* vb   = (__bf16*)(ws + 20 * MB);         // 4 MB
    __bf16* vt   = (__bf16*)(ws + 24 * MB);         // 4 MB
    __bf16* ob   = (__bf16*)(ws + 28 * MB);         // 4 MB
    __bf16* wqt  = (__bf16*)(ws + 32 * MB);
    __bf16* wkt  = (__bf16*)(ws + 32 * MB + 8192);
    __bf16* wvt  = (__bf16*)(ws + 32 * MB + 16384);
    __bf16* wpt  = (__bf16*)(ws + 32 * MB + 24576);
    float*  gpart = (float*)(ws + 32 * MB + 32768); // 16 KB

    transpose_w<<<4, 256, 0, stream>>>(wq, wk, wv, wp, wqt, wkt, wvt, wpt);
    gn_partial<<<256, 256, 0, stream>>>(x, gpart);
    gn_norm<<<256, 256, 0, stream>>>(x, gpart, gamma, beta, h32, h16);
    qkv_kernel<<<512, 256, 0, stream>>>(h16, wqt, wkt, wvt, bq, bk, bv, qb, kb, vb);
    vt_kernel<<<512, 256, 0, stream>>>(vb, vt);
    attn_kernel<<<512, 256, 0, stream>>>(qb, kb, vt, ob);
    final_kernel<<<512, 256, 0, stream>>>(ob, wpt, bp, h32, out);
}

// Round 2
// 206.184 us; speedup vs baseline: 1.1325x; 1.1325x over previous
//
#include <hip/hip_runtime.h>

#define NTOK 4096
#define CH 64
#define LOG2E 1.4426950408889634f

typedef __bf16 bf8 __attribute__((ext_vector_type(8)));
typedef __bf16 bf4 __attribute__((ext_vector_type(4)));
typedef _Float16 h8 __attribute__((ext_vector_type(8)));
typedef _Float16 h4 __attribute__((ext_vector_type(4)));
typedef float f4 __attribute__((ext_vector_type(4)));

__device__ __forceinline__ f4 mfma16(bf8 a, bf8 b, f4 c) {
    return __builtin_amdgcn_mfma_f32_16x16x32_bf16(a, b, c, 0, 0, 0);
}
__device__ __forceinline__ f4 mfma16h(h4 a, h4 b, f4 c) {
    return __builtin_amdgcn_mfma_f32_16x16x16f16(a, b, c, 0, 0, 0);
}

// ---------------- weight transpose + bf16 convert (grid 4, block 256) ----------------
__global__ void transpose_w(const float* __restrict__ wq, const float* __restrict__ wk,
                            const float* __restrict__ wv, const float* __restrict__ wp,
                            __bf16* __restrict__ wqt, __bf16* __restrict__ wkt,
                            __bf16* __restrict__ wvt, __bf16* __restrict__ wpt) {
    int m = blockIdx.x;
    const float* src = (m == 0) ? wq : (m == 1) ? wk : (m == 2) ? wv : wp;
    __bf16* dst      = (m == 0) ? wqt : (m == 1) ? wkt : (m == 2) ? wvt : wpt;
    __shared__ float s[64][65];
    int t = threadIdx.x;
    for (int i = 0; i < 16; ++i) {
        int e = i * 256 + t;
        s[e >> 6][e & 63] = src[e];   // s[in][out]
    }
    __syncthreads();
    int out = t >> 2, seg = t & 3;
    for (int j = 0; j < 16; ++j) {
        int in = seg * 16 + j;
        dst[out * 64 + in] = (__bf16)s[in][out];   // dst[out][in]
    }
}

// ---------------- GroupNorm stage 1: partial sums (grid 256 = 8b x 32 slabs) ----------------
__global__ __launch_bounds__(256) void gn_partial(const float* __restrict__ x,
                                                  float* __restrict__ gpart) {
    int t = threadIdx.x;
    int b = blockIdx.x >> 5, slab = blockIdx.x & 31;
    const float4* xb = (const float4*)(x + (size_t)(b * NTOK + slab * 128) * CH);
    float s = 0.f, ss = 0.f;
    for (int i = 0; i < 8; ++i) {
        int row = (t >> 4) + i * 16;          // 0..127
        float4 v = xb[row * 16 + (t & 15)];   // 4 channels, within one group
        s  += v.x + v.y + v.z + v.w;
        ss += v.x * v.x + v.y * v.y + v.z * v.z + v.w * v.w;
    }
    __shared__ float ls[256], lss[256];
    ls[t] = s; lss[t] = ss;
    __syncthreads();
    if (t < 8) {   // group t: contributors have (t&15) in {2t, 2t+1}
        float a = 0.f, aa = 0.f;
        for (int p = 0; p < 16; ++p) {
            a  += ls[p * 16 + 2 * t]  + ls[p * 16 + 2 * t + 1];
            aa += lss[p * 16 + 2 * t] + lss[p * 16 + 2 * t + 1];
        }
        gpart[((b * 32 + slab) * 8 + t) * 2 + 0] = a;
        gpart[((b * 32 + slab) * 8 + t) * 2 + 1] = aa;
    }
}

// ---------------- GroupNorm stage 2: finalize stats + normalize ----------------
__global__ __launch_bounds__(256) void gn_norm(const float* __restrict__ x,
                                               const float* __restrict__ gpart,
                                               const float* __restrict__ gamma,
                                               const float* __restrict__ beta,
                                               float* __restrict__ h32,
                                               __bf16* __restrict__ h16) {
    int t = threadIdx.x;
    int b = blockIdx.x >> 5, slab = blockIdx.x & 31;
    __shared__ float smean[8], srstd[8], sg[64], sb[64];
    if (t < 64) { sg[t] = gamma[t]; sb[t] = beta[t]; }
    if (t < 8) {
        float a = 0.f, aa = 0.f;
        for (int p = 0; p < 32; ++p) {
            a  += gpart[((b * 32 + p) * 8 + t) * 2 + 0];
            aa += gpart[((b * 32 + p) * 8 + t) * 2 + 1];
        }
        float mean = a * (1.f / 32768.f);
        float var = aa * (1.f / 32768.f) - mean * mean;
        smean[t] = mean;
        srstd[t] = rsqrtf(var + 1e-3f);
    }
    __syncthreads();
    size_t base = (size_t)(b * NTOK + slab * 128) * CH;
    const float4* xb = (const float4*)(x + base);
    float4* hb = (float4*)(h32 + base);
    __bf16* h16b = h16 + base;
    int c4 = (t & 15) * 4, g = c4 >> 3;
    float mean = smean[g], rstd = srstd[g];
    for (int i = 0; i < 8; ++i) {
        int row = (t >> 4) + i * 16;
        int idx = row * 16 + (t & 15);
        float4 v = xb[idx];
        float4 hv;
        hv.x = (v.x - mean) * rstd * sg[c4 + 0] + sb[c4 + 0];
        hv.y = (v.y - mean) * rstd * sg[c4 + 1] + sb[c4 + 1];
        hv.z = (v.z - mean) * rstd * sg[c4 + 2] + sb[c4 + 2];
        hv.w = (v.w - mean) * rstd * sg[c4 + 3] + sb[c4 + 3];
        hb[idx] = hv;
        bf4 hv16;
        hv16[0] = (__bf16)hv.x; hv16[1] = (__bf16)hv.y;
        hv16[2] = (__bf16)hv.z; hv16[3] = (__bf16)hv.w;
        *(bf4*)(h16b + (size_t)idx * 4) = hv16;
    }
}

// ---------------- fused QKV projection (grid 512, 64 rows/block) ----------------
// q,k written bf16 row-major; V written DIRECTLY as fp16 V^T [b][d][tok]
__global__ __launch_bounds__(256) void qkv_kernel(const __bf16* __restrict__ h16,
                                                  const __bf16* __restrict__ wqt,
                                                  const __bf16* __restrict__ wkt,
                                                  const __bf16* __restrict__ wvt,
                                                  const float* __restrict__ bq,
                                                  const float* __restrict__ bk,
                                                  const float* __restrict__ bv,
                                                  __bf16* __restrict__ q,
                                                  __bf16* __restrict__ k,
                                                  _Float16* __restrict__ vT) {
    __shared__ __bf16 W[3][64][72];   // [mat][out][in], +8 pad
    int t = threadIdx.x;
    for (int m = 0; m < 3; ++m) {
        const __bf16* src = (m == 0) ? wqt : (m == 1) ? wkt : wvt;
        for (int i = 0; i < 2; ++i) {
            int idx = i * 256 + t, row = idx >> 3, ch = idx & 7;
            *(bf8*)&W[m][row][ch * 8] = *(const bf8*)(src + row * 64 + ch * 8);
        }
    }
    __syncthreads();
    int lane = t & 63, wave = t >> 6, quad = lane >> 4, l15 = lane & 15;
    size_t rowbase = (size_t)blockIdx.x * 64 + wave * 16;
    int batch = (int)(rowbase >> 12);          // 64-row block never crosses batch
    int rloc  = (int)(rowbase & 4095);
    const __bf16* hrow = h16 + (rowbase + l15) * 64;
    bf8 a0 = *(const bf8*)(hrow + quad * 8);
    bf8 a1 = *(const bf8*)(hrow + 32 + quad * 8);
    for (int m = 0; m < 3; ++m) {
        const float* bias = (m == 0) ? bq : (m == 1) ? bk : bv;
        float sc = (m == 0) ? 0.125f * LOG2E : 1.0f;  // fold C^-0.5 and log2(e) into q
        for (int tt = 0; tt < 4; ++tt) {
            int col = l15 + 16 * tt;
            bf8 b0 = *(const bf8*)&W[m][col][quad * 8];
            bf8 b1 = *(const bf8*)&W[m][col][32 + quad * 8];
            f4 acc = {0.f, 0.f, 0.f, 0.f};
            acc = mfma16(a0, b0, acc);
            acc = mfma16(a1, b1, acc);
            float bb = bias[col];
            if (m == 2) {
                _Float16* vcol = vT + ((size_t)batch * 64 + col) * NTOK + rloc + quad * 4;
                for (int r = 0; r < 4; ++r) vcol[r] = (_Float16)(acc[r] + bb);
            } else {
                __bf16* dst = (m == 0) ? q : k;
                for (int r = 0; r < 4; ++r) {
                    float val = (acc[r] + bb) * sc;
                    dst[(rowbase + quad * 4 + r) * 64 + col] = (__bf16)val;
                }
            }
        }
    }
}

// ---------------- flash attention v2 (grid 512 = 8b x 64 q-tiles; 512 thr = 4 qsub x 2 kc)
// S^T formulation: lane owns ONE q-row (l15); P never leaves registers.
__global__ __launch_bounds__(512, 8) void attn_kernel(const __bf16* __restrict__ q,
                                                      const __bf16* __restrict__ k,
                                                      const _Float16* __restrict__ vT,
                                                      __bf16* __restrict__ o) {
    __shared__ __align__(16) char smem[36864];
    __bf16 (*Kl)[64][72]    = (__bf16 (*)[64][72])smem;              // [2 kc][key][d]
    _Float16 (*Vl)[64][72]  = (_Float16 (*)[64][72])(smem + 18432);  // [2 kc][d][key]

    int t = threadIdx.x;
    int b = blockIdx.x >> 6, qt = blockIdx.x & 63;
    int lane = t & 63, wave = t >> 6, quad = lane >> 4, l15 = lane & 15;
    int qsub = wave & 3, g = wave >> 2;   // g = key-chunk (0..1), threads [g*256, g*256+256)
    int tg = t & 255;

    const __bf16* qrow = q + ((size_t)b * NTOK + qt * 64 + qsub * 16 + l15) * 64;
    bf8 aq0 = *(const bf8*)(qrow + quad * 8);
    bf8 aq1 = *(const bf8*)(qrow + 32 + quad * 8);

    const __bf16* kbase   = k  + (size_t)b * NTOK * 64;
    const _Float16* vbase = vT + (size_t)b * 64 * NTOK;

    f4 acc[4] = {{0,0,0,0},{0,0,0,0},{0,0,0,0},{0,0,0,0}};  // O^T[d=16td+quad*4+r][q=l15]
    float mi = -1e30f, li = 0.f;

    for (int it = 0; it < 32; ++it) {
        int key0 = g * 2048 + it * 64;
        __syncthreads();
        // stage K tile [64key][64d] and V^T tile [64d][64key] (group-private)
        for (int i = 0; i < 2; ++i) {
            int e = i * 256 + tg, row = e >> 3, ch = e & 7;
            *(bf8*)&Kl[g][row][ch * 8] = *(const bf8*)(kbase + (size_t)(key0 + row) * 64 + ch * 8);
            *(h8*)&Vl[g][row][ch * 8]  = *(const h8*)(vbase + (size_t)row * NTOK + key0 + ch * 8);
        }
        __syncthreads();

        // S^T = K·Q^T : C-layout col=l15=q, row=quad*4+r=key (within 16-key tile t4)
        f4 St[4];
        for (int t4 = 0; t4 < 4; ++t4) {
            bf8 k0 = *(const bf8*)&Kl[g][t4 * 16 + l15][quad * 8];
            bf8 k1 = *(const bf8*)&Kl[g][t4 * 16 + l15][32 + quad * 8];
            f4 a = {0.f, 0.f, 0.f, 0.f};
            a = mfma16(k0, aq0, a);
            a = mfma16(k1, aq1, a);
            St[t4] = a;
        }
        // online softmax: per-lane scalar state for q=l15; reduce across quads only
        float mloc = fmaxf(fmaxf(fmaxf(St[0][0], St[0][1]), fmaxf(St[0][2], St[0][3])),
                           fmaxf(fmaxf(St[1][0], St[1][1]), fmaxf(St[1][2], St[1][3])));
        mloc = fmaxf(mloc, fmaxf(fmaxf(fmaxf(St[2][0], St[2][1]), fmaxf(St[2][2], St[2][3])),
                                 fmaxf(fmaxf(St[3][0], St[3][1]), fmaxf(St[3][2], St[3][3]))));
        mloc = fmaxf(mloc, __shfl_xor(mloc, 16));
        mloc = fmaxf(mloc, __shfl_xor(mloc, 32));
        float mn = fmaxf(mi, mloc);
        float alpha = __builtin_amdgcn_exp2f(mi - mn);
        mi = mn;
        float rs = 0.f;
        h4 pf[4];
        for (int t4 = 0; t4 < 4; ++t4)
            for (int r = 0; r < 4; ++r) {
                float pv = __builtin_amdgcn_exp2f(St[t4][r] - mn);
                rs += pv;
                pf[t4][r] = (_Float16)pv;
            }
        rs += __shfl_xor(rs, 16);
        rs += __shfl_xor(rs, 32);
        li = li * alpha + rs;
        for (int td = 0; td < 4; ++td) acc[td] *= alpha;

        // O^T += V^T · P^T via 16x16x16 f16 MFMA; P already in B-frag layout!
        for (int t4 = 0; t4 < 4; ++t4)
            for (int td = 0; td < 4; ++td) {
                h4 vf = *(const h4*)&Vl[g][td * 16 + l15][t4 * 16 + quad * 4];
                acc[td] = mfma16h(vf, pf[t4], acc[td]);
            }
    }

    // combine the two key-chunks (log-sum-exp merge) via LDS (aliases staging bufs)
    __syncthreads();
    float* EO = (float*)smem;                      // [4 qsub][64 d][16 q] = 16 KB
    float* Em = (float*)(smem + 16384);            // [4][16]
    float* El = (float*)(smem + 16384 + 256);      // [4][16]
    if (g == 1) {
        for (int td = 0; td < 4; ++td)
            for (int r = 0; r < 4; ++r)
                EO[(qsub * 64 + td * 16 + quad * 4 + r) * 16 + l15] = acc[td][r];
        if (quad == 0) { Em[qsub * 16 + l15] = mi; El[qsub * 16 + l15] = li; }
    }
    __syncthreads();
    if (g == 0) {
        float m1 = Em[qsub * 16 + l15], l1 = El[qsub * 16 + l15];
        float M = fmaxf(mi, m1);
        float a0 = __builtin_amdgcn_exp2f(mi - M);
        float a1 = __builtin_amdgcn_exp2f(m1 - M);
        float inv = 1.f / (li * a0 + l1 * a1);
        __bf16* orow = o + ((size_t)b * NTOK + qt * 64 + qsub * 16 + l15) * 64;
        for (int td = 0; td < 4; ++td) {
            bf4 ov;
            for (int r = 0; r < 4; ++r) {
                float ec = EO[(qsub * 64 + td * 16 + quad * 4 + r) * 16 + l15];
                ov[r] = (__bf16)((acc[td][r] * a0 + ec * a1) * inv);
            }
            *(bf4*)(orow + td * 16 + quad * 4) = ov;
        }
    }
}

// ---------------- final projection + bias + residual (grid 512) ----------------
__global__ __launch_bounds__(256) void final_kernel(const __bf16* __restrict__ o,
                                                    const __bf16* __restrict__ wpt,
                                                    const float* __restrict__ bp,
                                                    const float* __restrict__ h32,
                                                    float* __restrict__ out) {
    __shared__ __bf16 W[64][72];
    int t = threadIdx.x;
    for (int i = 0; i < 2; ++i) {
        int idx = i * 256 + t, row = idx >> 3, ch = idx & 7;
        *(bf8*)&W[row][ch * 8] = *(const bf8*)(wpt + row * 64 + ch * 8);
    }
    __syncthreads();
    int lane = t & 63, wave = t >> 6, quad = lane >> 4, l15 = lane & 15;
    size_t rowbase = (size_t)blockIdx.x * 64 + wave * 16;
    const __bf16* orow = o + (rowbase + l15) * 64;
    bf8 a0 = *(const bf8*)(orow + quad * 8);
    bf8 a1 = *(const bf8*)(orow + 32 + quad * 8);
    for (int tt = 0; tt < 4; ++tt) {
        int col = l15 + 16 * tt;
        bf8 b0 = *(const bf8*)&W[col][quad * 8];
        bf8 b1 = *(const bf8*)&W[col][32 + quad * 8];
        f4 acc = {0.f,0.f,0.f,0.f};
        acc = mfma16(a0, b0, acc);
        acc = mfma16(a1, b1, acc);
        float bias = bp[col];
        for (int r = 0; r < 4; ++r) {
            size_t gi = (rowbase + quad * 4 + r) * 64 + col;
            out[gi] = acc[r] + bias + h32[gi];
        }
    }
}

extern "C" void kernel_launch(void* const* d_in, const int* in_sizes, int n_in,
                              void* d_out, int out_size, void* d_ws, size_t ws_size,
                              hipStream_t stream) {
    const float* x     = (const float*)d_in[0];
    const float* gamma = (const float*)d_in[1];
    const float* beta  = (const float*)d_in[2];
    const float* wq    = (const float*)d_in[3];
    const float* bq    = (const float*)d_in[4];
    const float* wk    = (const float*)d_in[5];
    const float* bk    = (const float*)d_in[6];
    const float* wv    = (const float*)d_in[7];
    const float* bv    = (const float*)d_in[8];
    const float* wp    = (const float*)d_in[9];
    const float* bp    = (const float*)d_in[10];
    float* out = (float*)d_out;

    char* ws = (char*)d_ws;
    const size_t MB = 1024 * 1024;
    float*    h32 = (float*)(ws);                  // 8 MB
    __bf16*   h16 = (__bf16*)(ws + 8 * MB);        // 4 MB
    __bf16*   qb  = (__bf16*)(ws + 12 * MB);       // 4 MB
    __bf16*   kb  = (__bf16*)(ws + 16 * MB);       // 4 MB
    _Float16* vtb = (_Float16*)(ws + 20 * MB);     // 4 MB  (V^T fp16)
    __bf16*   ob  = (__bf16*)(ws + 24 * MB);       // 4 MB
    __bf16*   wqt = (__bf16*)(ws + 28 * MB);
    __bf16*   wkt = (__bf16*)(ws + 28 * MB + 8192);
    __bf16*   wvt = (__bf16*)(ws + 28 * MB + 16384);
    __bf16*   wpt = (__bf16*)(ws + 28 * MB + 24576);
    float*    gpart = (float*)(ws + 28 * MB + 32768); // 16 KB

    transpose_w<<<4, 256, 0, stream>>>(wq, wk, wv, wp, wqt, wkt, wvt, wpt);
    gn_partial<<<256, 256, 0, stream>>>(x, gpart);
    gn_norm<<<256, 256, 0, stream>>>(x, gpart, gamma, beta, h32, h16);
    qkv_kernel<<<512, 256, 0, stream>>>(h16, wqt, wkt, wvt, bq, bk, bv, qb, kb, vtb);
    attn_kernel<<<512, 512, 0, stream>>>(qb, kb, vtb, ob);
    final_kernel<<<512, 256, 0, stream>>>(ob, wpt, bp, h32, out);
}

// Round 3
// 173.997 us; speedup vs baseline: 1.3420x; 1.1850x over previous
//
#include <hip/hip_runtime.h>

#define NTOK 4096
#define CH 64
#define LOG2E 1.4426950408889634f

typedef __bf16 bf8 __attribute__((ext_vector_type(8)));
typedef __bf16 bf4 __attribute__((ext_vector_type(4)));
typedef _Float16 h8 __attribute__((ext_vector_type(8)));
typedef _Float16 h4 __attribute__((ext_vector_type(4)));
typedef float f4 __attribute__((ext_vector_type(4)));

__device__ __forceinline__ f4 mfma16(bf8 a, bf8 b, f4 c) {
    return __builtin_amdgcn_mfma_f32_16x16x32_bf16(a, b, c, 0, 0, 0);
}
__device__ __forceinline__ f4 mfma16h(h4 a, h4 b, f4 c) {
    return __builtin_amdgcn_mfma_f32_16x16x16f16(a, b, c, 0, 0, 0);
}

// ---------------- GroupNorm stage 1: partial sums (grid 512 = 8b x 64 slabs of 64 rows) ----
__global__ __launch_bounds__(256) void gn_partial(const float* __restrict__ x,
                                                  float* __restrict__ gpart) {
    int t = threadIdx.x;
    int b = blockIdx.x >> 6, slab = blockIdx.x & 63;
    const float4* xb = (const float4*)(x + (size_t)(b * NTOK + slab * 64) * CH);
    float s = 0.f, ss = 0.f;
    for (int i = 0; i < 4; ++i) {
        int row = (t >> 4) + i * 16;          // 0..63
        float4 v = xb[row * 16 + (t & 15)];   // 4 channels within one group
        s  += v.x + v.y + v.z + v.w;
        ss += v.x * v.x + v.y * v.y + v.z * v.z + v.w * v.w;
    }
    __shared__ float ls[256], lss[256];
    ls[t] = s; lss[t] = ss;
    __syncthreads();
    if (t < 8) {   // group t: contributors have (t&15) in {2t, 2t+1}
        float a = 0.f, aa = 0.f;
        for (int p = 0; p < 16; ++p) {
            a  += ls[p * 16 + 2 * t]  + ls[p * 16 + 2 * t + 1];
            aa += lss[p * 16 + 2 * t] + lss[p * 16 + 2 * t + 1];
        }
        gpart[((b * 64 + slab) * 8 + t) * 2 + 0] = a;
        gpart[((b * 64 + slab) * 8 + t) * 2 + 1] = aa;
    }
}

// ---------------- weight transpose + bf16 convert + GN stats finalize (grid 5) -----------
__global__ void transpose_w_fin(const float* __restrict__ wq, const float* __restrict__ wk,
                                const float* __restrict__ wv, const float* __restrict__ wp,
                                const float* __restrict__ gpart,
                                __bf16* __restrict__ wqt, __bf16* __restrict__ wkt,
                                __bf16* __restrict__ wvt, __bf16* __restrict__ wpt,
                                float* __restrict__ stats) {
    int m = blockIdx.x;
    int t = threadIdx.x;
    if (m == 4) {   // GN stats finalize: 64 (batch,group) pairs
        if (t < 64) {
            int b = t >> 3, gi = t & 7;
            float a = 0.f, aa = 0.f;
            for (int p = 0; p < 64; ++p) {
                a  += gpart[((b * 64 + p) * 8 + gi) * 2 + 0];
                aa += gpart[((b * 64 + p) * 8 + gi) * 2 + 1];
            }
            float mean = a * (1.f / 32768.f);
            float var = aa * (1.f / 32768.f) - mean * mean;
            stats[t * 2 + 0] = mean;
            stats[t * 2 + 1] = rsqrtf(var + 1e-3f);
        }
        return;
    }
    const float* src = (m == 0) ? wq : (m == 1) ? wk : (m == 2) ? wv : wp;
    __bf16* dst      = (m == 0) ? wqt : (m == 1) ? wkt : (m == 2) ? wvt : wpt;
    __shared__ float s[64][65];
    for (int i = 0; i < 16; ++i) {
        int e = i * 256 + t;
        s[e >> 6][e & 63] = src[e];   // s[in][out]
    }
    __syncthreads();
    int out = t >> 2, seg = t & 3;
    for (int j = 0; j < 16; ++j) {
        int in = seg * 16 + j;
        dst[out * 64 + in] = (__bf16)s[in][out];   // dst[out][in]
    }
}

// ---------------- fused GN + QKV projection (grid 512, 64 rows/block) --------------------
// applies GroupNorm on the fly; q,k bf16 row-major; V written as fp16 V^T via LDS transpose
__global__ __launch_bounds__(256) void qkv_gn(const float* __restrict__ x,
                                              const float* __restrict__ stats,
                                              const float* __restrict__ gamma,
                                              const float* __restrict__ beta,
                                              const __bf16* __restrict__ wqt,
                                              const __bf16* __restrict__ wkt,
                                              const __bf16* __restrict__ wvt,
                                              const float* __restrict__ bq,
                                              const float* __restrict__ bk,
                                              const float* __restrict__ bv,
                                              __bf16* __restrict__ q,
                                              __bf16* __restrict__ k,
                                              _Float16* __restrict__ vT) {
    __shared__ __bf16 W[3][64][72];     // [mat][out][in]
    __shared__ __bf16 Hl[64][72];       // normalized tile [tok][ch]
    __shared__ _Float16 Vst[64][68];    // V^T staging [d][tok]
    int t = threadIdx.x;
    for (int m = 0; m < 3; ++m) {
        const __bf16* src = (m == 0) ? wqt : (m == 1) ? wkt : wvt;
        for (int i = 0; i < 2; ++i) {
            int e = i * 256 + t, row = e >> 3, ch = e & 7;
            *(bf8*)&W[m][row][ch * 8] = *(const bf8*)(src + row * 64 + ch * 8);
        }
    }
    size_t rowbase = (size_t)blockIdx.x * 64;
    int b = (int)(rowbase >> 12), tokbase = (int)(rowbase & 4095);
    // on-the-fly GroupNorm into Hl
    {
        int c4 = (t & 15) * 4, grp = c4 >> 3;
        float mean = stats[(b * 8 + grp) * 2], rstd = stats[(b * 8 + grp) * 2 + 1];
        float g0 = gamma[c4] * rstd, g1 = gamma[c4 + 1] * rstd,
              g2 = gamma[c4 + 2] * rstd, g3 = gamma[c4 + 3] * rstd;
        float b0 = beta[c4], b1 = beta[c4 + 1], b2 = beta[c4 + 2], b3 = beta[c4 + 3];
        const float4* xb = (const float4*)(x + rowbase * 64);
        for (int i = 0; i < 4; ++i) {
            int row = (t >> 4) + i * 16;
            float4 v = xb[row * 16 + (t & 15)];
            bf4 hv;
            hv[0] = (__bf16)((v.x - mean) * g0 + b0);
            hv[1] = (__bf16)((v.y - mean) * g1 + b1);
            hv[2] = (__bf16)((v.z - mean) * g2 + b2);
            hv[3] = (__bf16)((v.w - mean) * g3 + b3);
            *(bf4*)&Hl[row][c4] = hv;
        }
    }
    __syncthreads();
    int lane = t & 63, wave = t >> 6, quad = lane >> 4, l15 = lane & 15;
    bf8 a0 = *(const bf8*)&Hl[wave * 16 + l15][quad * 8];
    bf8 a1 = *(const bf8*)&Hl[wave * 16 + l15][32 + quad * 8];
    for (int m = 0; m < 3; ++m) {
        const float* bias = (m == 0) ? bq : (m == 1) ? bk : bv;
        float sc = (m == 0) ? 0.125f * LOG2E : 1.0f;
        for (int tt = 0; tt < 4; ++tt) {
            int col = l15 + 16 * tt;
            bf8 b0 = *(const bf8*)&W[m][col][quad * 8];
            bf8 b1 = *(const bf8*)&W[m][col][32 + quad * 8];
            f4 acc = {0.f, 0.f, 0.f, 0.f};
            acc = mfma16(a0, b0, acc);
            acc = mfma16(a1, b1, acc);
            float bb = bias[col];
            if (m == 2) {
                for (int r = 0; r < 4; ++r)
                    Vst[col][wave * 16 + quad * 4 + r] = (_Float16)(acc[r] + bb);
            } else {
                __bf16* dst = (m == 0) ? q : k;
                for (int r = 0; r < 4; ++r) {
                    float val = (acc[r] + bb) * sc;
                    dst[(rowbase + wave * 16 + quad * 4 + r) * 64 + col] = (__bf16)val;
                }
            }
        }
    }
    __syncthreads();
    // coalesced V^T writeout: thread -> (d = t>>2, seg = t&3), 16 contiguous tokens
    {
        int d = t >> 2, seg = t & 3;
        h4 c0 = *(const h4*)&Vst[d][seg * 16 + 0];
        h4 c1 = *(const h4*)&Vst[d][seg * 16 + 4];
        h4 c2 = *(const h4*)&Vst[d][seg * 16 + 8];
        h4 c3 = *(const h4*)&Vst[d][seg * 16 + 12];
        h8 o0 = {c0[0], c0[1], c0[2], c0[3], c1[0], c1[1], c1[2], c1[3]};
        h8 o1 = {c2[0], c2[1], c2[2], c2[3], c3[0], c3[1], c3[2], c3[3]};
        _Float16* dst = vT + ((size_t)b * 64 + d) * NTOK + tokbase + seg * 16;
        *(h8*)dst = o0;
        *(h8*)(dst + 8) = o1;
    }
}

// ---------------- flash attention v3 (grid 512; 1024 thr = 4 qsub x 4 key-chunks) --------
__global__ __launch_bounds__(1024, 8) void attn_kernel(const __bf16* __restrict__ q,
                                                       const __bf16* __restrict__ k,
                                                       const _Float16* __restrict__ vT,
                                                       __bf16* __restrict__ o) {
    __shared__ __align__(16) char smem[71680];   // 4 chunks x (Kl 9216 + Vl 8704)
    int t = threadIdx.x;
    int b = blockIdx.x >> 6, qt = blockIdx.x & 63;
    int lane = t & 63, wave = t >> 6, quad = lane >> 4, l15 = lane & 15;
    int qsub = wave & 3, g = wave >> 2;   // g = key-chunk 0..3
    int tg = t & 255;
    __bf16 (*Kl)[72]   = (__bf16 (*)[72])(smem + g * 17920);          // [key][d]
    _Float16 (*Vl)[68] = (_Float16 (*)[68])(smem + g * 17920 + 9216); // [d][key], stride 68

    const __bf16* qrow = q + ((size_t)b * NTOK + qt * 64 + qsub * 16 + l15) * 64;
    bf8 aq0 = *(const bf8*)(qrow + quad * 8);
    bf8 aq1 = *(const bf8*)(qrow + 32 + quad * 8);

    const __bf16* kbase   = k  + (size_t)b * NTOK * 64;
    const _Float16* vbase = vT + (size_t)b * 64 * NTOK;

    f4 acc[4] = {{0,0,0,0},{0,0,0,0},{0,0,0,0},{0,0,0,0}};  // O^T[d][q=l15]
    float mi = -1e30f, li = 0.f;

    for (int it = 0; it < 16; ++it) {
        int key0 = g * 1024 + it * 64;
        __syncthreads();
        for (int i = 0; i < 2; ++i) {
            int e = i * 256 + tg, row = e >> 3, ch = e & 7;
            *(bf8*)&Kl[row][ch * 8] = *(const bf8*)(kbase + (size_t)(key0 + row) * 64 + ch * 8);
            h8 v8 = *(const h8*)(vbase + (size_t)row * NTOK + key0 + ch * 8);
            h4 vlo = {v8[0], v8[1], v8[2], v8[3]};
            h4 vhi = {v8[4], v8[5], v8[6], v8[7]};
            *(h4*)&Vl[row][ch * 8 + 0] = vlo;
            *(h4*)&Vl[row][ch * 8 + 4] = vhi;
        }
        __syncthreads();

        // S^T = K·Q^T : col=l15=q, row=quad*4+r=key within 16-key tile t4
        f4 St[4];
        for (int t4 = 0; t4 < 4; ++t4) {
            bf8 k0 = *(const bf8*)&Kl[t4 * 16 + l15][quad * 8];
            bf8 k1 = *(const bf8*)&Kl[t4 * 16 + l15][32 + quad * 8];
            f4 a = {0.f, 0.f, 0.f, 0.f};
            a = mfma16(k0, aq0, a);
            a = mfma16(k1, aq1, a);
            St[t4] = a;
        }
        // online softmax (per-lane scalar state; reduce across quads: lanes ^16, ^32)
        float mloc = fmaxf(fmaxf(fmaxf(St[0][0], St[0][1]), fmaxf(St[0][2], St[0][3])),
                           fmaxf(fmaxf(St[1][0], St[1][1]), fmaxf(St[1][2], St[1][3])));
        mloc = fmaxf(mloc, fmaxf(fmaxf(fmaxf(St[2][0], St[2][1]), fmaxf(St[2][2], St[2][3])),
                                 fmaxf(fmaxf(St[3][0], St[3][1]), fmaxf(St[3][2], St[3][3]))));
        mloc = fmaxf(mloc, __shfl_xor(mloc, 16));
        mloc = fmaxf(mloc, __shfl_xor(mloc, 32));
        bool up = mloc > mi;
        float mn = fmaxf(mi, mloc);
        float rs = 0.f;
        h4 pf[4];
        for (int t4 = 0; t4 < 4; ++t4)
            for (int r = 0; r < 4; ++r) {
                float pv = __builtin_amdgcn_exp2f(St[t4][r] - mn);
                rs += pv;
                pf[t4][r] = (_Float16)pv;
            }
        rs += __shfl_xor(rs, 16);
        rs += __shfl_xor(rs, 32);
        if (__any(up)) {
            float alpha = __builtin_amdgcn_exp2f(mi - mn);
            li = li * alpha + rs;
            for (int td = 0; td < 4; ++td) acc[td] *= alpha;
        } else {
            li += rs;
        }
        mi = mn;

        // O^T += V^T · P^T ; P already in B-frag layout
        for (int t4 = 0; t4 < 4; ++t4)
            for (int td = 0; td < 4; ++td) {
                h4 vf = *(const h4*)&Vl[td * 16 + l15][t4 * 16 + quad * 4];
                acc[td] = mfma16h(vf, pf[t4], acc[td]);
            }
    }

    // 4-way log-sum-exp combine across key-chunks (aliases staging LDS)
    __syncthreads();
    float* EO = (float*)smem;                    // [3 chunks][256 rows][17] = 52224 B
    float* Em = (float*)(smem + 52224);          // [3][4][16]
    float* El = (float*)(smem + 52992);          // [3][4][16]
    if (g > 0) {
        int c = g - 1;
        for (int td = 0; td < 4; ++td)
            for (int r = 0; r < 4; ++r)
                EO[(c * 256 + qsub * 64 + td * 16 + quad * 4 + r) * 17 + l15] = acc[td][r];
        if (quad == 0) {
            Em[(c * 4 + qsub) * 16 + l15] = mi;
            El[(c * 4 + qsub) * 16 + l15] = li;
        }
    }
    __syncthreads();
    if (g == 0) {
        float m1 = Em[(0 * 4 + qsub) * 16 + l15], l1 = El[(0 * 4 + qsub) * 16 + l15];
        float m2 = Em[(1 * 4 + qsub) * 16 + l15], l2 = El[(1 * 4 + qsub) * 16 + l15];
        float m3 = Em[(2 * 4 + qsub) * 16 + l15], l3 = El[(2 * 4 + qsub) * 16 + l15];
        float M = fmaxf(fmaxf(mi, m1), fmaxf(m2, m3));
        float a0 = __builtin_amdgcn_exp2f(mi - M);
        float a1 = __builtin_amdgcn_exp2f(m1 - M);
        float a2 = __builtin_amdgcn_exp2f(m2 - M);
        float a3 = __builtin_amdgcn_exp2f(m3 - M);
        float inv = 1.f / (li * a0 + l1 * a1 + l2 * a2 + l3 * a3);
        __bf16* orow = o + ((size_t)b * NTOK + qt * 64 + qsub * 16 + l15) * 64;
        for (int td = 0; td < 4; ++td) {
            bf4 ov;
            for (int r = 0; r < 4; ++r) {
                int rr = qsub * 64 + td * 16 + quad * 4 + r;
                float val = acc[td][r] * a0
                          + EO[(0 * 256 + rr) * 17 + l15] * a1
                          + EO[(1 * 256 + rr) * 17 + l15] * a2
                          + EO[(2 * 256 + rr) * 17 + l15] * a3;
                ov[r] = (__bf16)(val * inv);
            }
            *(bf4*)(orow + td * 16 + quad * 4) = ov;
        }
    }
}

// ---------------- final projection + bias + GN-residual (grid 512) -----------------------
__global__ __launch_bounds__(256) void final_gn(const __bf16* __restrict__ o,
                                                const __bf16* __restrict__ wpt,
                                                const float* __restrict__ bp,
                                                const float* __restrict__ x,
                                                const float* __restrict__ stats,
                                                const float* __restrict__ gamma,
                                                const float* __restrict__ beta,
                                                float* __restrict__ out) {
    __shared__ __bf16 W[64][72];
    __shared__ float sm[8], sr[8], sg[64], sb[64];
    int t = threadIdx.x;
    size_t rowbase0 = (size_t)blockIdx.x * 64;
    int b = (int)(rowbase0 >> 12);
    for (int i = 0; i < 2; ++i) {
        int e = i * 256 + t, row = e >> 3, ch = e & 7;
        *(bf8*)&W[row][ch * 8] = *(const bf8*)(wpt + row * 64 + ch * 8);
    }
    if (t < 64) { sg[t] = gamma[t]; sb[t] = beta[t]; }
    if (t < 8)  { sm[t] = stats[(b * 8 + t) * 2]; sr[t] = stats[(b * 8 + t) * 2 + 1]; }
    __syncthreads();
    int lane = t & 63, wave = t >> 6, quad = lane >> 4, l15 = lane & 15;
    size_t rowbase = rowbase0 + wave * 16;
    const __bf16* orow = o + (rowbase + l15) * 64;
    bf8 a0 = *(const bf8*)(orow + quad * 8);
    bf8 a1 = *(const bf8*)(orow + 32 + quad * 8);
    for (int tt = 0; tt < 4; ++tt) {
        int col = l15 + 16 * tt;
        bf8 b0 = *(const bf8*)&W[col][quad * 8];
        bf8 b1 = *(const bf8*)&W[col][32 + quad * 8];
        f4 acc = {0.f, 0.f, 0.f, 0.f};
        acc = mfma16(a0, b0, acc);
        acc = mfma16(a1, b1, acc);
        int grp = col >> 3;
        float mean = sm[grp], gs = sg[col] * sr[grp], bs = sb[col];
        float bias = bp[col];
        for (int r = 0; r < 4; ++r) {
            size_t gi = (rowbase + quad * 4 + r) * 64 + col;
            float h = (x[gi] - mean) * gs + bs;
            out[gi] = acc[r] + bias + h;
        }
    }
}

extern "C" void kernel_launch(void* const* d_in, const int* in_sizes, int n_in,
                              void* d_out, int out_size, void* d_ws, size_t ws_size,
                              hipStream_t stream) {
    const float* x     = (const float*)d_in[0];
    const float* gamma = (const float*)d_in[1];
    const float* beta  = (const float*)d_in[2];
    const float* wq    = (const float*)d_in[3];
    const float* bq    = (const float*)d_in[4];
    const float* wk    = (const float*)d_in[5];
    const float* bk    = (const float*)d_in[6];
    const float* wv    = (const float*)d_in[7];
    const float* bv    = (const float*)d_in[8];
    const float* wp    = (const float*)d_in[9];
    const float* bp    = (const float*)d_in[10];
    float* out = (float*)d_out;

    char* ws = (char*)d_ws;
    const size_t MB = 1024 * 1024;
    __bf16*   qb  = (__bf16*)(ws);                 // 4 MB
    __bf16*   kb  = (__bf16*)(ws + 4 * MB);        // 4 MB
    _Float16* vtb = (_Float16*)(ws + 8 * MB);      // 4 MB (V^T fp16)
    __bf16*   ob  = (__bf16*)(ws + 12 * MB);       // 4 MB
    __bf16*   wqt = (__bf16*)(ws + 16 * MB);
    __bf16*   wkt = (__bf16*)(ws + 16 * MB + 8192);
    __bf16*   wvt = (__bf16*)(ws + 16 * MB + 16384);
    __bf16*   wpt = (__bf16*)(ws + 16 * MB + 24576);
    float*    gpart = (float*)(ws + 16 * MB + 32768);          // 32 KB
    float*    stats = (float*)(ws + 16 * MB + 32768 + 32768);  // 512 B

    gn_partial<<<512, 256, 0, stream>>>(x, gpart);
    transpose_w_fin<<<5, 256, 0, stream>>>(wq, wk, wv, wp, gpart, wqt, wkt, wvt, wpt, stats);
    qkv_gn<<<512, 256, 0, stream>>>(x, stats, gamma, beta, wqt, wkt, wvt, bq, bk, bv, qb, kb, vtb);
    attn_kernel<<<512, 1024, 0, stream>>>(qb, kb, vtb, ob);
    final_gn<<<512, 256, 0, stream>>>(ob, wpt, bp, x, stats, gamma, beta, out);
}